// Round 4
// baseline (316.913 us; speedup 1.0000x reference)
//
#include <hip/hip_runtime.h>

typedef unsigned short USHORT;
typedef short short8 __attribute__((ext_vector_type(8)));
typedef float f32x4 __attribute__((ext_vector_type(4)));

__device__ __forceinline__ float fast_sig(float x) {
  return __builtin_amdgcn_rcpf(1.f + __builtin_amdgcn_exp2f(x * -1.442695041f));
}
__device__ __forceinline__ USHORT f2b(float f) {   // fp32 -> bf16 RNE
  unsigned int u = __float_as_uint(f);
  unsigned int r = (u + 0x7fffu + ((u >> 16) & 1u)) >> 16;
  return (USHORT)r;
}

// =====================================================================
// K0a: repack conv weights (co,ci,3,3) fp32 -> wrep[kk][co][ci] bf16.
// =====================================================================
__global__ __launch_bounds__(256) void prep_w_k(
    const float* __restrict__ cw, USHORT* __restrict__ wrep) {
  const int idx = blockIdx.x * 256 + threadIdx.x;   // 0..147455
  const int kk = idx >> 14;
  const int co = (idx >> 7) & 127;
  const int ci = idx & 127;
  wrep[idx] = f2b(cw[(co * 128 + ci) * 9 + kk]);
}

// =====================================================================
// K0b: transpose x (b,ci,h,w) fp32 -> x_t[b][h][w][ci] bf16.
// grid 2048 = b(2) x h(128) x cq(8 chunks of 16 ci); block 256.
// =====================================================================
__global__ __launch_bounds__(256) void x2t_k(
    const float* __restrict__ x, USHORT* __restrict__ xt_g) {
  __shared__ USHORT lt[128 * 18];    // [w][ci16 pad18]
  const int tid = threadIdx.x;
  const int bid = blockIdx.x;
  const int cqi = bid & 7;
  const int h   = (bid >> 3) & 127;
  const int b   = bid >> 10;
  const int ci0 = cqi * 16;

  // phase A: coalesced float4 loads along w, scatter bf16 into lt
#pragma unroll
  for (int it = 0; it < 2; ++it) {
    int task = it * 256 + tid;        // 0..511
    int ci = task >> 5;               // 0..15
    int wq = task & 31;               // 0..31
    float4 v = ((const float4*)(x + ((size_t)((b * 128 + ci0 + ci) * 128 + h)) * 128))[wq];
    lt[(wq * 4 + 0) * 18 + ci] = f2b(v.x);
    lt[(wq * 4 + 1) * 18 + ci] = f2b(v.y);
    lt[(wq * 4 + 2) * 18 + ci] = f2b(v.z);
    lt[(wq * 4 + 3) * 18 + ci] = f2b(v.w);
  }
  __syncthreads();
  // phase B: write ci-contiguous pairs
  unsigned int* dst = (unsigned int*)xt_g + ((size_t)((b * 128 + h) * 128)) * 64 + cqi * 8;
#pragma unroll
  for (int it = 0; it < 4; ++it) {
    int task = it * 256 + tid;        // 0..1023
    int w = task >> 3;                // 0..127
    int p = task & 7;                 // ci pair 0..7
    dst[(size_t)w * 64 + p] = *(const unsigned int*)&lt[w * 18 + 2 * p];
  }
}

// =====================================================================
// K1: 3x3 conv as implicit-GEMM MFMA (bf16 in, fp32 acc).
// grid 512 = wh(2) * h(128) * b(2); block 256 (4 waves).
// Persistent LDS tile xt[dh 3][wl 72][ci 136pad] bf16, staged once from x_t.
// Wave: 64 co x 32 w; K = 9 taps x 128 ci.
// =====================================================================
__global__ __launch_bounds__(256) void conv_mfma_k(
    const USHORT* __restrict__ xt_g, const USHORT* __restrict__ wrep,
    const float* __restrict__ cb, float* __restrict__ y) {
  __shared__ USHORT xt[3 * 72 * 136];   // 58752 B

  const int tid = threadIdx.x;
  const int bid = blockIdx.x;
  const int wh  = bid & 1;
  const int h   = (bid >> 1) & 127;
  const int b   = bid >> 8;
  const int w0  = wh * 64;

  const int wv   = tid >> 6;
  const int lane = tid & 63;
  const int m    = lane & 15;
  const int kg   = lane >> 4;
  const int co0w = (wv & 1) * 64;
  const int ws0  = (wv >> 1) * 32;

  // ---- stage x_t[b, h-1..h+1, w0-4..w0+67, 0..127] once ----
  for (int it = 0; it < 14; ++it) {
    int task = it * 256 + tid;          // 0..3455 : (dh 3)(wl 72)(cq 16)
    if (task < 3456) {
      int dh  = task / 1152;
      int rem = task - dh * 1152;
      int wl  = rem >> 4;
      int cq  = task & 15;
      int wg  = w0 - 4 + wl;
      int hh  = h + dh - 1;
      uint4 v = make_uint4(0u, 0u, 0u, 0u);
      if (((unsigned)wg < 128u) && ((unsigned)hh < 128u))
        v = *(const uint4*)(xt_g + ((size_t)((b * 128 + hh) * 128 + wg)) * 128 + cq * 8);
      *(uint4*)&xt[(dh * 72 + wl) * 136 + cq * 8] = v;
    }
  }
  __syncthreads();

  f32x4 acc[4][2];
#pragma unroll
  for (int s = 0; s < 4; ++s)
#pragma unroll
    for (int ws = 0; ws < 2; ++ws) acc[s][ws] = (f32x4){0.f, 0.f, 0.f, 0.f};

  const USHORT* wrow = wrep + (co0w + m) * 128 + kg * 8;
  const int xbase = ws0 + m + 3;

  for (int c = 0; c < 4; ++c) {
#pragma unroll
    for (int t9 = 0; t9 < 9; ++t9) {
      const int kh = t9 / 3, kw = t9 - kh * 3;
      short8 a[4];
#pragma unroll
      for (int s = 0; s < 4; ++s)
        a[s] = *(const short8*)(wrow + t9 * 16384 + s * 2048 + c * 32);
#pragma unroll
      for (int ws = 0; ws < 2; ++ws) {
        short8 bf = *(const short8*)&xt[(kh * 72 + xbase + ws * 16 + kw) * 136 + c * 32 + kg * 8];
#pragma unroll
        for (int s = 0; s < 4; ++s)
          acc[s][ws] = __builtin_amdgcn_mfma_f32_16x16x32_bf16(a[s], bf, acc[s][ws], 0, 0, 0);
      }
    }
  }

  // ---- epilogue: bias + store fp32 y ----
#pragma unroll
  for (int s = 0; s < 4; ++s) {
#pragma unroll
    for (int ws = 0; ws < 2; ++ws) {
      const int w = w0 + ws0 + ws * 16 + m;
#pragma unroll
      for (int r = 0; r < 4; ++r) {
        const int co = co0w + s * 16 + kg * 4 + r;
        y[((size_t)((b * 128 + co) * 128 + h)) * 128 + w] = acc[s][ws][r] + cb[co];
      }
    }
  }
}

// =====================================================================
// K2: Mamba, 8 seqs/block, thread = (s = tid>>5, ch = tid&31).
// Weights in registers; activations through LDS as b128 broadcasts;
// transcendentals via raw v_exp/v_log/v_rcp builtins.
// =====================================================================
__global__ __launch_bounds__(256, 3) void mamba_k(
    const float* __restrict__ y,
    const float* __restrict__ w_in, const float* __restrict__ c1w,
    const float* __restrict__ c1b, const float* __restrict__ xpw,
    const float* __restrict__ dtw, const float* __restrict__ dtb,
    const float* __restrict__ alog, const float* __restrict__ dvec,
    const float* __restrict__ wout,
    float* __restrict__ m, float* __restrict__ stats) {
  __shared__ float ylds[8 * 128];
  __shared__ float xcs[64 * 32];
  __shared__ float dt0s[64];
  __shared__ float Bs[64 * 16];
  __shared__ float Cs[64 * 16];
  __shared__ float yms[64 * 32];
  __shared__ float reds[8];

  const int tid = threadIdx.x;
  const int s   = tid >> 5;
  const int ch  = tid & 31;

  // stage y (one seq = 128 consecutive floats)
  *(float4*)&ylds[tid * 4] = ((const float4*)(y + (size_t)blockIdx.x * 1024))[tid];

  // in_proj weight columns ch and ch+32 -> registers
  float wia[16], wiz[16];
#pragma unroll
  for (int q = 0; q < 4; ++q) {
    float4 va = ((const float4*)(w_in + ch * 16))[q];
    float4 vz = ((const float4*)(w_in + (ch + 32) * 16))[q];
    wia[q * 4 + 0] = va.x; wia[q * 4 + 1] = va.y; wia[q * 4 + 2] = va.z; wia[q * 4 + 3] = va.w;
    wiz[q * 4 + 0] = vz.x; wiz[q * 4 + 1] = vz.y; wiz[q * 4 + 2] = vz.z; wiz[q * 4 + 3] = vz.w;
  }
  const float4 cwv = *(const float4*)(c1w + ch * 4);
  const float cbr = c1b[ch];
  const float dwv = dtw[ch], dbv = dtb[ch], Dv = dvec[ch];

  __syncthreads();

  const float* yr = &ylds[s * 128];
  float xi[8], zg[8];
#pragma unroll
  for (int l = 0; l < 8; ++l) {
    float4 q0 = *(const float4*)(yr + l * 16 + 0);
    float4 q1 = *(const float4*)(yr + l * 16 + 4);
    float4 q2 = *(const float4*)(yr + l * 16 + 8);
    float4 q3 = *(const float4*)(yr + l * 16 + 12);
    float ax = q0.x * wia[0] + q0.y * wia[1] + q0.z * wia[2] + q0.w * wia[3]
             + q1.x * wia[4] + q1.y * wia[5] + q1.z * wia[6] + q1.w * wia[7]
             + q2.x * wia[8] + q2.y * wia[9] + q2.z * wia[10] + q2.w * wia[11]
             + q3.x * wia[12] + q3.y * wia[13] + q3.z * wia[14] + q3.w * wia[15];
    float az = q0.x * wiz[0] + q0.y * wiz[1] + q0.z * wiz[2] + q0.w * wiz[3]
             + q1.x * wiz[4] + q1.y * wiz[5] + q1.z * wiz[6] + q1.w * wiz[7]
             + q2.x * wiz[8] + q2.y * wiz[9] + q2.z * wiz[10] + q2.w * wiz[11]
             + q3.x * wiz[12] + q3.y * wiz[13] + q3.z * wiz[14] + q3.w * wiz[15];
    xi[l] = ax; zg[l] = az;
  }

  // causal depthwise conv1d (k=4) + SiLU
  float xc[8];
#pragma unroll
  for (int l = 0; l < 8; ++l) {
    float a = fmaf(cwv.w, xi[l], cbr);
    if (l >= 1) a = fmaf(cwv.z, xi[l - 1], a);
    if (l >= 2) a = fmaf(cwv.y, xi[l - 2], a);
    if (l >= 3) a = fmaf(cwv.x, xi[l - 3], a);
    float sc = a * fast_sig(a);
    xc[l] = sc;
    xcs[(s * 8 + l) * 32 + ch] = sc;
  }
  __syncthreads();

  // x_proj: every lane computes j=ch and j=32 (lane0 publishes the latter)
  {
    float xpv[32], xpv2[32];
#pragma unroll
    for (int q = 0; q < 8; ++q) {
      float4 v  = ((const float4*)(xpw + ch * 32))[q];
      float4 v2 = ((const float4*)(xpw + 32 * 32))[q];
      xpv[q * 4 + 0] = v.x;  xpv[q * 4 + 1] = v.y;  xpv[q * 4 + 2] = v.z;  xpv[q * 4 + 3] = v.w;
      xpv2[q * 4 + 0] = v2.x; xpv2[q * 4 + 1] = v2.y; xpv2[q * 4 + 2] = v2.z; xpv2[q * 4 + 3] = v2.w;
    }
#pragma unroll
    for (int l = 0; l < 8; ++l) {
      const float* xr = &xcs[(s * 8 + l) * 32];
      float xv[32];
#pragma unroll
      for (int q = 0; q < 8; ++q) {
        float4 v = *(const float4*)(xr + q * 4);
        xv[q * 4 + 0] = v.x; xv[q * 4 + 1] = v.y; xv[q * 4 + 2] = v.z; xv[q * 4 + 3] = v.w;
      }
      float a = 0.f, a2 = 0.f;
#pragma unroll
      for (int d = 0; d < 32; ++d) {
        a  = fmaf(xv[d], xpv[d],  a);
        a2 = fmaf(xv[d], xpv2[d], a2);
      }
      if (ch == 0)       { dt0s[s * 8 + l] = a; Cs[(s * 8 + l) * 16 + 15] = a2; }
      else if (ch <= 16)   Bs[(s * 8 + l) * 16 + (ch - 1)]  = a;
      else                 Cs[(s * 8 + l) * 16 + (ch - 17)] = a;
    }
  }
  __syncthreads();

  // selective scan (register state), then gate
  float A2r[16];
#pragma unroll
  for (int q = 0; q < 4; ++q) {
    float4 av = ((const float4*)(alog + ch * 16))[q];
    A2r[q * 4 + 0] = -__builtin_amdgcn_exp2f(av.x * 1.442695041f) * 1.442695041f;
    A2r[q * 4 + 1] = -__builtin_amdgcn_exp2f(av.y * 1.442695041f) * 1.442695041f;
    A2r[q * 4 + 2] = -__builtin_amdgcn_exp2f(av.z * 1.442695041f) * 1.442695041f;
    A2r[q * 4 + 3] = -__builtin_amdgcn_exp2f(av.w * 1.442695041f) * 1.442695041f;
  }
  float hreg[16];
#pragma unroll
  for (int st = 0; st < 16; ++st) hreg[st] = 0.f;
#pragma unroll
  for (int l = 0; l < 8; ++l) {
    const int tok = s * 8 + l;
    float pre = fmaf(dt0s[tok], dwv, dbv);
    float t = __builtin_amdgcn_exp2f(pre * 1.442695041f);
    float dtl = 0.6931471806f * __builtin_amdgcn_logf(1.f + t);
    dtl = (pre > 20.f) ? pre : dtl;
    float dtxc = dtl * xc[l];
    float Bv[16], Cv[16];
#pragma unroll
    for (int q = 0; q < 4; ++q) {
      float4 bv = *(const float4*)&Bs[tok * 16 + q * 4];
      float4 cv = *(const float4*)&Cs[tok * 16 + q * 4];
      Bv[q * 4 + 0] = bv.x; Bv[q * 4 + 1] = bv.y; Bv[q * 4 + 2] = bv.z; Bv[q * 4 + 3] = bv.w;
      Cv[q * 4 + 0] = cv.x; Cv[q * 4 + 1] = cv.y; Cv[q * 4 + 2] = cv.z; Cv[q * 4 + 3] = cv.w;
    }
    float yl = 0.f;
#pragma unroll
    for (int st = 0; st < 16; ++st) {
      float aa = __builtin_amdgcn_exp2f(dtl * A2r[st]);
      hreg[st] = fmaf(aa, hreg[st], dtxc * Bv[st]);
      yl = fmaf(hreg[st], Cv[st], yl);
    }
    float ymv = fmaf(Dv, xc[l], yl) * (zg[l] * fast_sig(zg[l]));
    yms[tok * 32 + ch] = ymv;
  }
  __syncthreads();

  // out_proj: thread -> e = ch&15, 4 l values; GN stats partials
  const int e  = ch & 15;
  const int lg = ch >> 4;
  const int n  = blockIdx.x * 8 + s;
  float wo[32];
#pragma unroll
  for (int q = 0; q < 8; ++q) {
    float4 v = ((const float4*)(wout + e * 32))[q];
    wo[q * 4 + 0] = v.x; wo[q * 4 + 1] = v.y; wo[q * 4 + 2] = v.z; wo[q * 4 + 3] = v.w;
  }
  float ls = 0.f, lq = 0.f;
  float* mrow = m + (size_t)n * 128;
#pragma unroll
  for (int i = 0; i < 4; ++i) {
    const int l = lg * 4 + i;
    const float* ymr = &yms[(s * 8 + l) * 32];
    float yv[32];
#pragma unroll
    for (int q = 0; q < 8; ++q) {
      float4 v = *(const float4*)(ymr + q * 4);
      yv[q * 4 + 0] = v.x; yv[q * 4 + 1] = v.y; yv[q * 4 + 2] = v.z; yv[q * 4 + 3] = v.w;
    }
    float a = 0.f;
#pragma unroll
    for (int d = 0; d < 32; ++d) a = fmaf(yv[d], wo[d], a);
    mrow[l * 16 + e] = a;
    ls += a;
    lq = fmaf(a, a, lq);
  }
#pragma unroll
  for (int off = 32; off > 0; off >>= 1) {
    ls += __shfl_down(ls, off);
    lq += __shfl_down(lq, off);
  }
  const int wid = tid >> 6;
  if ((tid & 63) == 0) { reds[wid * 2] = ls; reds[wid * 2 + 1] = lq; }
  __syncthreads();
  if (tid == 0) {
    float S = reds[0] + reds[2] + reds[4] + reds[6];
    float Q = reds[1] + reds[3] + reds[5] + reds[7];
    int bb = n >> 14;
    int cc = (n >> 7) & 127;
    int gg = cc >> 5;
    atomicAdd(&stats[(bb * 4 + gg) * 2 + 0], S);
    atomicAdd(&stats[(bb * 4 + gg) * 2 + 1], Q);
  }
}

// =====================================================================
// K3: GroupNorm finalize + SiLU + residual, in-place on d_out.
// =====================================================================
__global__ __launch_bounds__(256) void gn_silu_k(
    const float* __restrict__ x,
    const float* __restrict__ gnw, const float* __restrict__ gnb,
    const float* __restrict__ stats, float* __restrict__ out) {
  const int idx0 = (blockIdx.x * 256 + threadIdx.x) * 4;
  const int bb = idx0 >> 21;
  const int cc = (idx0 >> 14) & 127;
  const int gg = cc >> 5;
  const float S = stats[(bb * 4 + gg) * 2 + 0];
  const float Q = stats[(bb * 4 + gg) * 2 + 1];
  const float inv  = 1.0f / 524288.0f;
  const float mu   = S * inv;
  const float var  = fmaf(Q, inv, -mu * mu);
  const float rstd = rsqrtf(var + 1e-5f);
  const float gw  = gnw[cc] * rstd;
  const float gb2 = gnb[cc] - mu * gw;

  float4 mv = *(const float4*)(out + idx0);
  float4 xv = *(const float4*)(x + idx0);
  float mvv[4] = { mv.x, mv.y, mv.z, mv.w };
  float xf[4]  = { xv.x, xv.y, xv.z, xv.w };
  float res[4];
#pragma unroll
  for (int j = 0; j < 4; ++j) {
    float nv = fmaf(mvv[j], gw, gb2);
    float sv = nv * fast_sig(nv);
    res[j] = xf[j] + sv;
  }
  *(float4*)(out + idx0) = make_float4(res[0], res[1], res[2], res[3]);
}

// =====================================================================
extern "C" void kernel_launch(void* const* d_in, const int* in_sizes, int n_in,
                              void* d_out, int out_size, void* d_ws, size_t ws_size,
                              hipStream_t stream) {
  const float* x     = (const float*)d_in[0];
  const float* convw = (const float*)d_in[1];
  const float* convb = (const float*)d_in[2];
  const float* gnw   = (const float*)d_in[3];
  const float* gnb   = (const float*)d_in[4];
  const float* winp  = (const float*)d_in[5];
  const float* c1w   = (const float*)d_in[6];
  const float* c1b   = (const float*)d_in[7];
  const float* xpw   = (const float*)d_in[8];
  const float* dtw   = (const float*)d_in[9];
  const float* dtb   = (const float*)d_in[10];
  const float* alog  = (const float*)d_in[11];
  const float* dvec  = (const float*)d_in[12];
  const float* wout  = (const float*)d_in[13];

  float*  y     = (float*)d_ws;                       // 16 MB
  float*  stats = y + 4194304;                        // 64 B
  // d_out (16 MB) doubles as prep scratch until mamba overwrites it:
  USHORT* xt_g  = (USHORT*)d_out;                     // 8 MB  (x transposed, bf16)
  USHORT* wrep  = (USHORT*)d_out + 4194304;           // 288 KB (weights, bf16)
  float*  m     = (float*)d_out;                      // mamba output, finalized in place

  hipMemsetAsync(stats, 0, 16 * sizeof(float), stream);
  hipLaunchKernelGGL(prep_w_k, dim3(576), dim3(256), 0, stream, convw, wrep);
  hipLaunchKernelGGL(x2t_k, dim3(2048), dim3(256), 0, stream, x, xt_g);
  hipLaunchKernelGGL(conv_mfma_k, dim3(512), dim3(256), 0, stream, xt_g, wrep, convb, y);
  hipLaunchKernelGGL(mamba_k, dim3(4096), dim3(256), 0, stream,
                     y, winp, c1w, c1b, xpw, dtw, dtb, alog, dvec, wout, m, stats);
  hipLaunchKernelGGL(gn_silu_k, dim3(4096), dim3(256), 0, stream,
                     x, gnw, gnb, stats, (float*)d_out);
}

// Round 5
// 293.189 us; speedup vs baseline: 1.0809x; 1.0809x over previous
//
#include <hip/hip_runtime.h>

typedef unsigned short USHORT;
typedef short short8 __attribute__((ext_vector_type(8)));
typedef float f32x4 __attribute__((ext_vector_type(4)));

__device__ __forceinline__ float fast_sig(float x) {
  return __builtin_amdgcn_rcpf(1.f + __builtin_amdgcn_exp2f(x * -1.442695041f));
}
__device__ __forceinline__ USHORT f2b(float f) {   // fp32 -> bf16 RNE
  unsigned int u = __float_as_uint(f);
  unsigned int r = (u + 0x7fffu + ((u >> 16) & 1u)) >> 16;
  return (USHORT)r;
}

// =====================================================================
// K0a: repack conv weights (co,ci,3,3) fp32 -> wrep[kk][co][ci] bf16.
// =====================================================================
__global__ __launch_bounds__(256) void prep_w_k(
    const float* __restrict__ cw, USHORT* __restrict__ wrep) {
  const int idx = blockIdx.x * 256 + threadIdx.x;   // 0..147455
  const int kk = idx >> 14;
  const int co = (idx >> 7) & 127;
  const int ci = idx & 127;
  wrep[idx] = f2b(cw[(co * 128 + ci) * 9 + kk]);
}

// =====================================================================
// K0b: transpose x (b,ci,h,w) fp32 -> x_t[b][h][w][ci] bf16.
// grid 2048 = b(2) x h(128) x cq(8 chunks of 16 ci); block 256.
// =====================================================================
__global__ __launch_bounds__(256) void x2t_k(
    const float* __restrict__ x, USHORT* __restrict__ xt_g) {
  __shared__ USHORT lt[128 * 18];    // [w][ci16 pad18]
  const int tid = threadIdx.x;
  const int bid = blockIdx.x;
  const int cqi = bid & 7;
  const int h   = (bid >> 3) & 127;
  const int b   = bid >> 10;
  const int ci0 = cqi * 16;

#pragma unroll
  for (int it = 0; it < 2; ++it) {
    int task = it * 256 + tid;        // 0..511
    int ci = task >> 5;               // 0..15
    int wq = task & 31;               // 0..31
    float4 v = ((const float4*)(x + ((size_t)((b * 128 + ci0 + ci) * 128 + h)) * 128))[wq];
    lt[(wq * 4 + 0) * 18 + ci] = f2b(v.x);
    lt[(wq * 4 + 1) * 18 + ci] = f2b(v.y);
    lt[(wq * 4 + 2) * 18 + ci] = f2b(v.z);
    lt[(wq * 4 + 3) * 18 + ci] = f2b(v.w);
  }
  __syncthreads();
  unsigned int* dst = (unsigned int*)xt_g + ((size_t)((b * 128 + h) * 128)) * 64 + cqi * 8;
#pragma unroll
  for (int it = 0; it < 4; ++it) {
    int task = it * 256 + tid;        // 0..1023
    int w = task >> 3;                // 0..127
    int p = task & 7;                 // ci pair 0..7
    dst[(size_t)w * 64 + p] = *(const unsigned int*)&lt[w * 18 + 2 * p];
  }
}

// =====================================================================
// K1: 3x3 conv as implicit-GEMM MFMA (bf16 in, fp32 acc).
// grid 1024 = wq(4) * h(128) * b(2); block 256 (4 waves) => 4 blocks/CU.
// LDS tile xt[dh 3][wl 40][ci 136pad] bf16 (32.6 KB), staged once.
// Wave: 64 co x 16 w; K = 9 taps x 128 ci; 144 MFMAs/wave.
// =====================================================================
__global__ __launch_bounds__(256) void conv_mfma_k(
    const USHORT* __restrict__ xt_g, const USHORT* __restrict__ wrep,
    const float* __restrict__ cb, float* __restrict__ y) {
  __shared__ USHORT xt[3 * 40 * 136];   // 32640 B

  const int tid = threadIdx.x;
  const int bid = blockIdx.x;
  const int wq  = bid & 3;
  const int h   = (bid >> 2) & 127;
  const int b   = bid >> 9;
  const int w0  = wq * 32;

  const int wv   = tid >> 6;
  const int lane = tid & 63;
  const int m    = lane & 15;
  const int kg   = lane >> 4;
  const int co0w = (wv & 1) * 64;
  const int ws0  = (wv >> 1) * 16;

  // ---- stage x_t[b, h-1..h+1, w0-4..w0+35, 0..127] once ----
  for (int it = 0; it < 8; ++it) {
    int task = it * 256 + tid;          // 0..1919 : (dh 3)(wl 40)(cq 16)
    if (task < 1920) {
      int dh  = task / 640;
      int rem = task - dh * 640;
      int wl  = rem >> 4;
      int cq  = task & 15;
      int wg  = w0 - 4 + wl;
      int hh  = h + dh - 1;
      uint4 v = make_uint4(0u, 0u, 0u, 0u);
      if (((unsigned)wg < 128u) && ((unsigned)hh < 128u))
        v = *(const uint4*)(xt_g + ((size_t)((b * 128 + hh) * 128 + wg)) * 128 + cq * 8);
      *(uint4*)&xt[(dh * 40 + wl) * 136 + cq * 8] = v;
    }
  }
  __syncthreads();

  f32x4 acc[4];
#pragma unroll
  for (int s = 0; s < 4; ++s) acc[s] = (f32x4){0.f, 0.f, 0.f, 0.f};

  const USHORT* wrow = wrep + (co0w + m) * 128 + kg * 8;
  const int xbase = ws0 + m + 3;

  for (int c = 0; c < 4; ++c) {
#pragma unroll
    for (int t9 = 0; t9 < 9; ++t9) {
      const int kh = t9 / 3, kw = t9 - kh * 3;
      short8 a[4];
#pragma unroll
      for (int s = 0; s < 4; ++s)
        a[s] = *(const short8*)(wrow + t9 * 16384 + s * 2048 + c * 32);
      short8 bf = *(const short8*)&xt[(kh * 40 + xbase + kw) * 136 + c * 32 + kg * 8];
#pragma unroll
      for (int s = 0; s < 4; ++s)
        acc[s] = __builtin_amdgcn_mfma_f32_16x16x32_bf16(a[s], bf, acc[s], 0, 0, 0);
    }
  }

  // ---- epilogue: bias + store fp32 y ----
  const int w = w0 + ws0 + m;
#pragma unroll
  for (int s = 0; s < 4; ++s) {
#pragma unroll
    for (int r = 0; r < 4; ++r) {
      const int co = co0w + s * 16 + kg * 4 + r;
      y[((size_t)((b * 128 + co) * 128 + h)) * 128 + w] = acc[s][r] + cb[co];
    }
  }
}

// =====================================================================
// K2: Mamba, 8 seqs/block, thread = (s = tid>>5, ch = tid&31).
// Phase-local register weights (no spill: plain launch_bounds), LDS for
// activation exchange (b128), raw transcendental builtins.
// =====================================================================
__global__ __launch_bounds__(256) void mamba_k(
    const float* __restrict__ y,
    const float* __restrict__ w_in, const float* __restrict__ c1w,
    const float* __restrict__ c1b, const float* __restrict__ xpw,
    const float* __restrict__ dtw, const float* __restrict__ dtb,
    const float* __restrict__ alog, const float* __restrict__ dvec,
    const float* __restrict__ wout,
    float* __restrict__ m, float* __restrict__ stats) {
  __shared__ float ylds[8 * 128];     // 4 KB
  __shared__ float xcs[64 * 32];      // 8 KB (re-used as yms after scan)
  __shared__ float dt0s[64];
  __shared__ float Bs[64 * 16];       // 4 KB
  __shared__ float Cs[64 * 16];       // 4 KB
  __shared__ float reds[8];
  float* yms = xcs;                   // alias: xcs dead after x_proj phase

  const int tid = threadIdx.x;
  const int s   = tid >> 5;
  const int ch  = tid & 31;

  // stage y (one seq = 128 consecutive floats)
  *(float4*)&ylds[tid * 4] = ((const float4*)(y + (size_t)blockIdx.x * 1024))[tid];

  // in_proj weight columns ch and ch+32 -> registers (phase-local)
  float wia[16], wiz[16];
#pragma unroll
  for (int q = 0; q < 4; ++q) {
    float4 va = ((const float4*)(w_in + ch * 16))[q];
    float4 vz = ((const float4*)(w_in + (ch + 32) * 16))[q];
    wia[q * 4 + 0] = va.x; wia[q * 4 + 1] = va.y; wia[q * 4 + 2] = va.z; wia[q * 4 + 3] = va.w;
    wiz[q * 4 + 0] = vz.x; wiz[q * 4 + 1] = vz.y; wiz[q * 4 + 2] = vz.z; wiz[q * 4 + 3] = vz.w;
  }
  const float4 cwv = *(const float4*)(c1w + ch * 4);
  const float cbr = c1b[ch];
  const float dwv = dtw[ch], dbv = dtb[ch], Dv = dvec[ch];

  __syncthreads();

  const float* yr = &ylds[s * 128];
  float xi[8], zg[8];
#pragma unroll
  for (int l = 0; l < 8; ++l) {
    float4 q0 = *(const float4*)(yr + l * 16 + 0);
    float4 q1 = *(const float4*)(yr + l * 16 + 4);
    float4 q2 = *(const float4*)(yr + l * 16 + 8);
    float4 q3 = *(const float4*)(yr + l * 16 + 12);
    float ax = q0.x * wia[0] + q0.y * wia[1] + q0.z * wia[2] + q0.w * wia[3]
             + q1.x * wia[4] + q1.y * wia[5] + q1.z * wia[6] + q1.w * wia[7]
             + q2.x * wia[8] + q2.y * wia[9] + q2.z * wia[10] + q2.w * wia[11]
             + q3.x * wia[12] + q3.y * wia[13] + q3.z * wia[14] + q3.w * wia[15];
    float az = q0.x * wiz[0] + q0.y * wiz[1] + q0.z * wiz[2] + q0.w * wiz[3]
             + q1.x * wiz[4] + q1.y * wiz[5] + q1.z * wiz[6] + q1.w * wiz[7]
             + q2.x * wiz[8] + q2.y * wiz[9] + q2.z * wiz[10] + q2.w * wiz[11]
             + q3.x * wiz[12] + q3.y * wiz[13] + q3.z * wiz[14] + q3.w * wiz[15];
    xi[l] = ax; zg[l] = az;
  }

  // causal depthwise conv1d (k=4) + SiLU
  float xc[8];
#pragma unroll
  for (int l = 0; l < 8; ++l) {
    float a = fmaf(cwv.w, xi[l], cbr);
    if (l >= 1) a = fmaf(cwv.z, xi[l - 1], a);
    if (l >= 2) a = fmaf(cwv.y, xi[l - 2], a);
    if (l >= 3) a = fmaf(cwv.x, xi[l - 3], a);
    float sc = a * fast_sig(a);
    xc[l] = sc;
    xcs[(s * 8 + l) * 32 + ch] = sc;
  }
  __syncthreads();

  // x_proj main: thread (s,ch) computes column j=ch for its 8 tokens
  {
    float xpv[32];
#pragma unroll
    for (int q = 0; q < 8; ++q) {
      float4 v = ((const float4*)(xpw + ch * 32))[q];
      xpv[q * 4 + 0] = v.x; xpv[q * 4 + 1] = v.y; xpv[q * 4 + 2] = v.z; xpv[q * 4 + 3] = v.w;
    }
#pragma unroll
    for (int l = 0; l < 8; ++l) {
      const float* xr = &xcs[(s * 8 + l) * 32];
      float a = 0.f;
#pragma unroll
      for (int q = 0; q < 8; ++q) {
        float4 v = *(const float4*)(xr + q * 4);
        a = fmaf(v.x, xpv[q * 4 + 0], a);
        a = fmaf(v.y, xpv[q * 4 + 1], a);
        a = fmaf(v.z, xpv[q * 4 + 2], a);
        a = fmaf(v.w, xpv[q * 4 + 3], a);
      }
      if (ch == 0)       dt0s[s * 8 + l] = a;
      else if (ch <= 16) Bs[(s * 8 + l) * 16 + (ch - 1)]  = a;
      else               Cs[(s * 8 + l) * 16 + (ch - 17)] = a;
    }
  }
  // x_proj aux: j=32 (last C column) for all 64 tokens, threads tid<64.
  // Weight addresses are lane-invariant -> scalar loads, no reg arrays.
  if (tid < 64) {
    const float* xr = &xcs[tid * 32];
    float a2 = 0.f;
#pragma unroll
    for (int q = 0; q < 8; ++q) {
      float4 wv = *(const float4*)(xpw + 1024 + q * 4);   // uniform
      float4 v  = *(const float4*)(xr + q * 4);
      a2 = fmaf(v.x, wv.x, a2);
      a2 = fmaf(v.y, wv.y, a2);
      a2 = fmaf(v.z, wv.z, a2);
      a2 = fmaf(v.w, wv.w, a2);
    }
    Cs[tid * 16 + 15] = a2;
  }
  __syncthreads();

  // selective scan (register state), gate, write yms (aliases xcs)
  float A2r[16];
#pragma unroll
  for (int q = 0; q < 4; ++q) {
    float4 av = ((const float4*)(alog + ch * 16))[q];
    A2r[q * 4 + 0] = -__builtin_amdgcn_exp2f(av.x * 1.442695041f) * 1.442695041f;
    A2r[q * 4 + 1] = -__builtin_amdgcn_exp2f(av.y * 1.442695041f) * 1.442695041f;
    A2r[q * 4 + 2] = -__builtin_amdgcn_exp2f(av.z * 1.442695041f) * 1.442695041f;
    A2r[q * 4 + 3] = -__builtin_amdgcn_exp2f(av.w * 1.442695041f) * 1.442695041f;
  }
  float hreg[16];
#pragma unroll
  for (int st = 0; st < 16; ++st) hreg[st] = 0.f;
  float ymv[8];
#pragma unroll
  for (int l = 0; l < 8; ++l) {
    const int tok = s * 8 + l;
    float pre = fmaf(dt0s[tok], dwv, dbv);
    float t = __builtin_amdgcn_exp2f(pre * 1.442695041f);
    float dtl = 0.6931471806f * __builtin_amdgcn_logf(1.f + t);
    dtl = (pre > 20.f) ? pre : dtl;
    float dtxc = dtl * xc[l];
    float yl = 0.f;
#pragma unroll
    for (int q = 0; q < 4; ++q) {
      float4 bv = *(const float4*)&Bs[tok * 16 + q * 4];
      float4 cv = *(const float4*)&Cs[tok * 16 + q * 4];
      float aa;
      aa = __builtin_amdgcn_exp2f(dtl * A2r[q * 4 + 0]);
      hreg[q * 4 + 0] = fmaf(aa, hreg[q * 4 + 0], dtxc * bv.x);
      yl = fmaf(hreg[q * 4 + 0], cv.x, yl);
      aa = __builtin_amdgcn_exp2f(dtl * A2r[q * 4 + 1]);
      hreg[q * 4 + 1] = fmaf(aa, hreg[q * 4 + 1], dtxc * bv.y);
      yl = fmaf(hreg[q * 4 + 1], cv.y, yl);
      aa = __builtin_amdgcn_exp2f(dtl * A2r[q * 4 + 2]);
      hreg[q * 4 + 2] = fmaf(aa, hreg[q * 4 + 2], dtxc * bv.z);
      yl = fmaf(hreg[q * 4 + 2], cv.z, yl);
      aa = __builtin_amdgcn_exp2f(dtl * A2r[q * 4 + 3]);
      hreg[q * 4 + 3] = fmaf(aa, hreg[q * 4 + 3], dtxc * bv.w);
      yl = fmaf(hreg[q * 4 + 3], cv.w, yl);
    }
    ymv[l] = fmaf(Dv, xc[l], yl) * (zg[l] * fast_sig(zg[l]));
  }
  __syncthreads();   // xcs reads (aux pass) done; safe to overwrite as yms
#pragma unroll
  for (int l = 0; l < 8; ++l) yms[(s * 8 + l) * 32 + ch] = ymv[l];
  __syncthreads();

  // out_proj: thread -> e = ch&15, 4 l values; GN stats partials
  const int e  = ch & 15;
  const int lg = ch >> 4;
  const int n  = blockIdx.x * 8 + s;
  float wo[32];
#pragma unroll
  for (int q = 0; q < 8; ++q) {
    float4 v = ((const float4*)(wout + e * 32))[q];
    wo[q * 4 + 0] = v.x; wo[q * 4 + 1] = v.y; wo[q * 4 + 2] = v.z; wo[q * 4 + 3] = v.w;
  }
  float ls = 0.f, lq = 0.f;
  float* mrow = m + (size_t)n * 128;
#pragma unroll
  for (int i = 0; i < 4; ++i) {
    const int l = lg * 4 + i;
    const float* ymr = &yms[(s * 8 + l) * 32];
    float a = 0.f;
#pragma unroll
    for (int q = 0; q < 8; ++q) {
      float4 v = *(const float4*)(ymr + q * 4);
      a = fmaf(v.x, wo[q * 4 + 0], a);
      a = fmaf(v.y, wo[q * 4 + 1], a);
      a = fmaf(v.z, wo[q * 4 + 2], a);
      a = fmaf(v.w, wo[q * 4 + 3], a);
    }
    mrow[l * 16 + e] = a;
    ls += a;
    lq = fmaf(a, a, lq);
  }
#pragma unroll
  for (int off = 32; off > 0; off >>= 1) {
    ls += __shfl_down(ls, off);
    lq += __shfl_down(lq, off);
  }
  const int wid = tid >> 6;
  if ((tid & 63) == 0) { reds[wid * 2] = ls; reds[wid * 2 + 1] = lq; }
  __syncthreads();
  if (tid == 0) {
    float S = reds[0] + reds[2] + reds[4] + reds[6];
    float Q = reds[1] + reds[3] + reds[5] + reds[7];
    int bb = n >> 14;
    int cc = (n >> 7) & 127;
    int gg = cc >> 5;
    atomicAdd(&stats[(bb * 4 + gg) * 2 + 0], S);
    atomicAdd(&stats[(bb * 4 + gg) * 2 + 1], Q);
  }
}

// =====================================================================
// K3: GroupNorm finalize + SiLU + residual, in-place on d_out.
// =====================================================================
__global__ __launch_bounds__(256) void gn_silu_k(
    const float* __restrict__ x,
    const float* __restrict__ gnw, const float* __restrict__ gnb,
    const float* __restrict__ stats, float* __restrict__ out) {
  const int idx0 = (blockIdx.x * 256 + threadIdx.x) * 4;
  const int bb = idx0 >> 21;
  const int cc = (idx0 >> 14) & 127;
  const int gg = cc >> 5;
  const float S = stats[(bb * 4 + gg) * 2 + 0];
  const float Q = stats[(bb * 4 + gg) * 2 + 1];
  const float inv  = 1.0f / 524288.0f;
  const float mu   = S * inv;
  const float var  = fmaf(Q, inv, -mu * mu);
  const float rstd = rsqrtf(var + 1e-5f);
  const float gw  = gnw[cc] * rstd;
  const float gb2 = gnb[cc] - mu * gw;

  float4 mv = *(const float4*)(out + idx0);
  float4 xv = *(const float4*)(x + idx0);
  float mvv[4] = { mv.x, mv.y, mv.z, mv.w };
  float xf[4]  = { xv.x, xv.y, xv.z, xv.w };
  float res[4];
#pragma unroll
  for (int j = 0; j < 4; ++j) {
    float nv = fmaf(mvv[j], gw, gb2);
    float sv = nv * fast_sig(nv);
    res[j] = xf[j] + sv;
  }
  *(float4*)(out + idx0) = make_float4(res[0], res[1], res[2], res[3]);
}

// =====================================================================
extern "C" void kernel_launch(void* const* d_in, const int* in_sizes, int n_in,
                              void* d_out, int out_size, void* d_ws, size_t ws_size,
                              hipStream_t stream) {
  const float* x     = (const float*)d_in[0];
  const float* convw = (const float*)d_in[1];
  const float* convb = (const float*)d_in[2];
  const float* gnw   = (const float*)d_in[3];
  const float* gnb   = (const float*)d_in[4];
  const float* winp  = (const float*)d_in[5];
  const float* c1w   = (const float*)d_in[6];
  const float* c1b   = (const float*)d_in[7];
  const float* xpw   = (const float*)d_in[8];
  const float* dtw   = (const float*)d_in[9];
  const float* dtb   = (const float*)d_in[10];
  const float* alog  = (const float*)d_in[11];
  const float* dvec  = (const float*)d_in[12];
  const float* wout  = (const float*)d_in[13];

  float*  y     = (float*)d_ws;                       // 16 MB
  float*  stats = y + 4194304;                        // 64 B
  // d_out (16 MB) doubles as prep scratch until mamba overwrites it:
  USHORT* xt_g  = (USHORT*)d_out;                     // 8 MB  (x transposed, bf16)
  USHORT* wrep  = (USHORT*)d_out + 4194304;           // 288 KB (weights, bf16)
  float*  m     = (float*)d_out;                      // mamba output, finalized in place

  hipMemsetAsync(stats, 0, 16 * sizeof(float), stream);
  hipLaunchKernelGGL(prep_w_k, dim3(576), dim3(256), 0, stream, convw, wrep);
  hipLaunchKernelGGL(x2t_k, dim3(2048), dim3(256), 0, stream, x, xt_g);
  hipLaunchKernelGGL(conv_mfma_k, dim3(1024), dim3(256), 0, stream, xt_g, wrep, convb, y);
  hipLaunchKernelGGL(mamba_k, dim3(4096), dim3(256), 0, stream,
                     y, winp, c1w, c1b, xpw, dtw, dtb, alog, dvec, wout, m, stats);
  hipLaunchKernelGGL(gn_silu_k, dim3(4096), dim3(256), 0, stream,
                     x, gnw, gnb, stats, (float*)d_out);
}

// Round 6
// 243.497 us; speedup vs baseline: 1.3015x; 1.2041x over previous
//
#include <hip/hip_runtime.h>

typedef unsigned short USHORT;
typedef short short8 __attribute__((ext_vector_type(8)));
typedef float f32x4 __attribute__((ext_vector_type(4)));

__device__ __forceinline__ float fast_sig(float x) {
  return __builtin_amdgcn_rcpf(1.f + __builtin_amdgcn_exp2f(x * -1.442695041f));
}
__device__ __forceinline__ USHORT f2b(float f) {   // fp32 -> bf16 RNE
  unsigned int u = __float_as_uint(f);
  unsigned int r = (u + 0x7fffu + ((u >> 16) & 1u)) >> 16;
  return (USHORT)r;
}

// =====================================================================
// K0a: repack conv weights (co,ci,3,3) fp32 -> coalesced A-frag layout:
// wrep[((c*9+t9)*8+st)*512 + (kg*16+m)*8 + j]  (st=co>>4, m=co&15,
// c=ci>>5, kg=(ci>>3)&3, j=ci&7).  One A-frag = 64 lanes x 16B contiguous.
// =====================================================================
__global__ __launch_bounds__(256) void prep_w_k(
    const float* __restrict__ cw, USHORT* __restrict__ wrep) {
  const int idx = blockIdx.x * 256 + threadIdx.x;   // 0..147455 = (co,ci,t9)
  const int t9 = idx % 9;
  const int r  = idx / 9;
  const int ci = r & 127;
  const int co = r >> 7;
  const int c  = ci >> 5;
  const int kg = (ci >> 3) & 3;
  const int j  = ci & 7;
  const int st = co >> 4;
  const int mm = co & 15;
  wrep[((c * 9 + t9) * 8 + st) * 512 + (kg * 16 + mm) * 8 + j] = f2b(cw[idx]);
}

// =====================================================================
// K0b: transpose x (b,ci,h,w) fp32 -> x_t[b][h][w][ci] bf16.
// grid 2048 = b(2) x h(128) x cq(8 chunks of 16 ci); block 256.
// =====================================================================
__global__ __launch_bounds__(256) void x2t_k(
    const float* __restrict__ x, USHORT* __restrict__ xt_g) {
  __shared__ USHORT lt[128 * 18];    // [w][ci16 pad18]
  const int tid = threadIdx.x;
  const int bid = blockIdx.x;
  const int cqi = bid & 7;
  const int h   = (bid >> 3) & 127;
  const int b   = bid >> 10;
  const int ci0 = cqi * 16;

#pragma unroll
  for (int it = 0; it < 2; ++it) {
    int task = it * 256 + tid;        // 0..511
    int ci = task >> 5;               // 0..15
    int wq = task & 31;               // 0..31
    float4 v = ((const float4*)(x + ((size_t)((b * 128 + ci0 + ci) * 128 + h)) * 128))[wq];
    lt[(wq * 4 + 0) * 18 + ci] = f2b(v.x);
    lt[(wq * 4 + 1) * 18 + ci] = f2b(v.y);
    lt[(wq * 4 + 2) * 18 + ci] = f2b(v.z);
    lt[(wq * 4 + 3) * 18 + ci] = f2b(v.w);
  }
  __syncthreads();
  unsigned int* dst = (unsigned int*)xt_g + ((size_t)((b * 128 + h) * 128)) * 64 + cqi * 8;
#pragma unroll
  for (int it = 0; it < 4; ++it) {
    int task = it * 256 + tid;        // 0..1023
    int w = task >> 3;                // 0..127
    int p = task & 7;                 // ci pair 0..7
    dst[(size_t)w * 64 + p] = *(const unsigned int*)&lt[w * 18 + 2 * p];
  }
}

// =====================================================================
// K1: 3x3 conv as implicit-GEMM MFMA (bf16 in, fp32 acc).
// grid 256 = h(128) * b(2)  => 1 block/CU; block 512 (8 waves).
// Block tile: 128 co x 128 w (full row) at fixed (b,h).
// LDS: xt[dh 3][wl 136][ci 136pad] bf16 = 111 KB, staged once.
// Wave: 64 co x 32 w = 4 co-strips x 2 w-subtiles; 288 MFMA/wave.
// A-frags: single coalesced 1KB global loads (wrep layout, L1/L2-hot).
// =====================================================================
__global__ __launch_bounds__(512) void conv_mfma_k(
    const USHORT* __restrict__ xt_g, const USHORT* __restrict__ wrep,
    const float* __restrict__ cb, float* __restrict__ y) {
  __shared__ USHORT xt[3 * 136 * 136];   // 110976 B

  const int tid = threadIdx.x;
  const int bid = blockIdx.x;
  const int h   = bid & 127;
  const int b   = bid >> 7;

  const int wv   = tid >> 6;          // wave 0..7
  const int lane = tid & 63;
  const int m    = lane & 15;
  const int kg   = lane >> 4;
  const int ch2  = wv & 1;            // co half
  const int co0w = ch2 * 64;
  const int ws0  = (wv >> 1) * 32;    // w base (0,32,64,96)

  // ---- stage x_t[b, h-1..h+1, w-4..w+131, ci 0..127] once ----
  for (int it = 0; it < 13; ++it) {
    int task = it * 512 + tid;          // 0..6527 : (dh 3)(wl 136)(cq 16)
    if (task < 6528) {
      int dh  = task / 2176;            // 2176 = 136*16
      int rem = task - dh * 2176;
      int wl  = rem >> 4;
      int cq  = task & 15;
      int wg  = wl - 4;
      int hh  = h + dh - 1;
      uint4 v = make_uint4(0u, 0u, 0u, 0u);
      if (((unsigned)wg < 128u) && ((unsigned)hh < 128u))
        v = *(const uint4*)(xt_g + ((size_t)((b * 128 + hh) * 128 + wg)) * 128 + cq * 8);
      *(uint4*)&xt[(dh * 136 + wl) * 136 + cq * 8] = v;
    }
  }
  __syncthreads();

  f32x4 acc[4][2];
#pragma unroll
  for (int s = 0; s < 4; ++s)
#pragma unroll
    for (int ws = 0; ws < 2; ++ws) acc[s][ws] = (f32x4){0.f, 0.f, 0.f, 0.f};

  for (int c = 0; c < 4; ++c) {
#pragma unroll
    for (int t9 = 0; t9 < 9; ++t9) {
      const int kh = t9 / 3, kw = t9 - kh * 3;
      const USHORT* wbase = wrep + (size_t)(((c * 9 + t9) * 8 + ch2 * 4) * 512) + lane * 8;
      short8 a[4];
#pragma unroll
      for (int s = 0; s < 4; ++s)
        a[s] = *(const short8*)(wbase + s * 512);
#pragma unroll
      for (int ws = 0; ws < 2; ++ws) {
        short8 bf = *(const short8*)&xt[(kh * 136 + ws0 + ws * 16 + m + kw + 3) * 136 + c * 32 + kg * 8];
#pragma unroll
        for (int s = 0; s < 4; ++s)
          acc[s][ws] = __builtin_amdgcn_mfma_f32_16x16x32_bf16(a[s], bf, acc[s][ws], 0, 0, 0);
      }
    }
  }

  // ---- epilogue: bias + store fp32 y ----
#pragma unroll
  for (int s = 0; s < 4; ++s) {
#pragma unroll
    for (int ws = 0; ws < 2; ++ws) {
      const int w = ws0 + ws * 16 + m;
#pragma unroll
      for (int r = 0; r < 4; ++r) {
        const int co = co0w + s * 16 + kg * 4 + r;
        y[((size_t)((b * 128 + co) * 128 + h)) * 128 + w] = acc[s][ws][r] + cb[co];
      }
    }
  }
}

// =====================================================================
// K2: Mamba, 8 seqs/block, thread = (s = tid>>5, ch = tid&31).
// Phase-local register weights, LDS b128 exchange, raw transcendentals.
// yms separate (no alias) -> scan writes it directly, 4 barriers total.
// =====================================================================
__global__ __launch_bounds__(256) void mamba_k(
    const float* __restrict__ y,
    const float* __restrict__ w_in, const float* __restrict__ c1w,
    const float* __restrict__ c1b, const float* __restrict__ xpw,
    const float* __restrict__ dtw, const float* __restrict__ dtb,
    const float* __restrict__ alog, const float* __restrict__ dvec,
    const float* __restrict__ wout,
    float* __restrict__ m, float* __restrict__ stats) {
  __shared__ float ylds[8 * 128];     // 4 KB
  __shared__ float xcs[64 * 32];      // 8 KB
  __shared__ float yms[64 * 32];      // 8 KB
  __shared__ float dt0s[64];
  __shared__ float Bs[64 * 16];       // 4 KB
  __shared__ float Cs[64 * 16];       // 4 KB
  __shared__ float reds[8];

  const int tid = threadIdx.x;
  const int s   = tid >> 5;
  const int ch  = tid & 31;

  // stage y (one seq = 128 consecutive floats)
  *(float4*)&ylds[tid * 4] = ((const float4*)(y + (size_t)blockIdx.x * 1024))[tid];

  // in_proj weight columns ch and ch+32 -> registers (phase-local)
  float wia[16], wiz[16];
#pragma unroll
  for (int q = 0; q < 4; ++q) {
    float4 va = ((const float4*)(w_in + ch * 16))[q];
    float4 vz = ((const float4*)(w_in + (ch + 32) * 16))[q];
    wia[q * 4 + 0] = va.x; wia[q * 4 + 1] = va.y; wia[q * 4 + 2] = va.z; wia[q * 4 + 3] = va.w;
    wiz[q * 4 + 0] = vz.x; wiz[q * 4 + 1] = vz.y; wiz[q * 4 + 2] = vz.z; wiz[q * 4 + 3] = vz.w;
  }
  const float4 cwv = *(const float4*)(c1w + ch * 4);
  const float cbr = c1b[ch];
  const float dwv = dtw[ch], dbv = dtb[ch], Dv = dvec[ch];

  __syncthreads();

  const float* yr = &ylds[s * 128];
  float xc[8], zs[8];
  {
    float x0 = 0.f, x1 = 0.f, x2 = 0.f;   // xi ring: l-1, l-2, l-3
#pragma unroll
    for (int l = 0; l < 8; ++l) {
      float4 q0 = *(const float4*)(yr + l * 16 + 0);
      float4 q1 = *(const float4*)(yr + l * 16 + 4);
      float4 q2 = *(const float4*)(yr + l * 16 + 8);
      float4 q3 = *(const float4*)(yr + l * 16 + 12);
      float ax = q0.x * wia[0] + q0.y * wia[1] + q0.z * wia[2] + q0.w * wia[3]
               + q1.x * wia[4] + q1.y * wia[5] + q1.z * wia[6] + q1.w * wia[7]
               + q2.x * wia[8] + q2.y * wia[9] + q2.z * wia[10] + q2.w * wia[11]
               + q3.x * wia[12] + q3.y * wia[13] + q3.z * wia[14] + q3.w * wia[15];
      float az = q0.x * wiz[0] + q0.y * wiz[1] + q0.z * wiz[2] + q0.w * wiz[3]
               + q1.x * wiz[4] + q1.y * wiz[5] + q1.z * wiz[6] + q1.w * wiz[7]
               + q2.x * wiz[8] + q2.y * wiz[9] + q2.z * wiz[10] + q2.w * wiz[11]
               + q3.x * wiz[12] + q3.y * wiz[13] + q3.z * wiz[14] + q3.w * wiz[15];
      // causal depthwise conv1d (k=4) + SiLU
      float a = fmaf(cwv.w, ax, cbr);
      if (l >= 1) a = fmaf(cwv.z, x0, a);
      if (l >= 2) a = fmaf(cwv.y, x1, a);
      if (l >= 3) a = fmaf(cwv.x, x2, a);
      float sc = a * fast_sig(a);
      xc[l] = sc;
      xcs[(s * 8 + l) * 32 + ch] = sc;
      zs[l] = az * fast_sig(az);          // silu(z), final gate factor
      x2 = x1; x1 = x0; x0 = ax;
    }
  }
  __syncthreads();

  // x_proj main: thread (s,ch) computes column j=ch for its 8 tokens
  {
    float xpv[32];
#pragma unroll
    for (int q = 0; q < 8; ++q) {
      float4 v = ((const float4*)(xpw + ch * 32))[q];
      xpv[q * 4 + 0] = v.x; xpv[q * 4 + 1] = v.y; xpv[q * 4 + 2] = v.z; xpv[q * 4 + 3] = v.w;
    }
#pragma unroll
    for (int l = 0; l < 8; ++l) {
      const float* xr = &xcs[(s * 8 + l) * 32];
      float a = 0.f;
#pragma unroll
      for (int q = 0; q < 8; ++q) {
        float4 v = *(const float4*)(xr + q * 4);
        a = fmaf(v.x, xpv[q * 4 + 0], a);
        a = fmaf(v.y, xpv[q * 4 + 1], a);
        a = fmaf(v.z, xpv[q * 4 + 2], a);
        a = fmaf(v.w, xpv[q * 4 + 3], a);
      }
      if (ch == 0)       dt0s[s * 8 + l] = a;
      else if (ch <= 16) Bs[(s * 8 + l) * 16 + (ch - 1)]  = a;
      else               Cs[(s * 8 + l) * 16 + (ch - 17)] = a;
    }
  }
  // x_proj aux: j=32 (last C column), uniform weight addresses
  if (tid < 64) {
    const float* xr = &xcs[tid * 32];
    float a2 = 0.f;
#pragma unroll
    for (int q = 0; q < 8; ++q) {
      float4 wv = *(const float4*)(xpw + 1024 + q * 4);   // uniform
      float4 v  = *(const float4*)(xr + q * 4);
      a2 = fmaf(v.x, wv.x, a2);
      a2 = fmaf(v.y, wv.y, a2);
      a2 = fmaf(v.z, wv.z, a2);
      a2 = fmaf(v.w, wv.w, a2);
    }
    Cs[tid * 16 + 15] = a2;
  }
  __syncthreads();

  // selective scan (register state), gate, write yms directly
  float A2r[16];
#pragma unroll
  for (int q = 0; q < 4; ++q) {
    float4 av = ((const float4*)(alog + ch * 16))[q];
    A2r[q * 4 + 0] = -__builtin_amdgcn_exp2f(av.x * 1.442695041f) * 1.442695041f;
    A2r[q * 4 + 1] = -__builtin_amdgcn_exp2f(av.y * 1.442695041f) * 1.442695041f;
    A2r[q * 4 + 2] = -__builtin_amdgcn_exp2f(av.z * 1.442695041f) * 1.442695041f;
    A2r[q * 4 + 3] = -__builtin_amdgcn_exp2f(av.w * 1.442695041f) * 1.442695041f;
  }
  float hreg[16];
#pragma unroll
  for (int st = 0; st < 16; ++st) hreg[st] = 0.f;
#pragma unroll
  for (int l = 0; l < 8; ++l) {
    const int tok = s * 8 + l;
    float pre = fmaf(dt0s[tok], dwv, dbv);
    float t = __builtin_amdgcn_exp2f(pre * 1.442695041f);
    float dtl = 0.6931471806f * __builtin_amdgcn_logf(1.f + t);
    dtl = (pre > 20.f) ? pre : dtl;
    float dtxc = dtl * xc[l];
    float yl = 0.f;
#pragma unroll
    for (int q = 0; q < 4; ++q) {
      float4 bv = *(const float4*)&Bs[tok * 16 + q * 4];
      float4 cv = *(const float4*)&Cs[tok * 16 + q * 4];
      float aa;
      aa = __builtin_amdgcn_exp2f(dtl * A2r[q * 4 + 0]);
      hreg[q * 4 + 0] = fmaf(aa, hreg[q * 4 + 0], dtxc * bv.x);
      yl = fmaf(hreg[q * 4 + 0], cv.x, yl);
      aa = __builtin_amdgcn_exp2f(dtl * A2r[q * 4 + 1]);
      hreg[q * 4 + 1] = fmaf(aa, hreg[q * 4 + 1], dtxc * bv.y);
      yl = fmaf(hreg[q * 4 + 1], cv.y, yl);
      aa = __builtin_amdgcn_exp2f(dtl * A2r[q * 4 + 2]);
      hreg[q * 4 + 2] = fmaf(aa, hreg[q * 4 + 2], dtxc * bv.z);
      yl = fmaf(hreg[q * 4 + 2], cv.z, yl);
      aa = __builtin_amdgcn_exp2f(dtl * A2r[q * 4 + 3]);
      hreg[q * 4 + 3] = fmaf(aa, hreg[q * 4 + 3], dtxc * bv.w);
      yl = fmaf(hreg[q * 4 + 3], cv.w, yl);
    }
    yms[tok * 32 + ch] = fmaf(Dv, xc[l], yl) * zs[l];
  }
  __syncthreads();

  // out_proj: thread -> e = ch&15, 4 l values; GN stats partials
  const int e  = ch & 15;
  const int lg = ch >> 4;
  const int n  = blockIdx.x * 8 + s;
  float wo[32];
#pragma unroll
  for (int q = 0; q < 8; ++q) {
    float4 v = ((const float4*)(wout + e * 32))[q];
    wo[q * 4 + 0] = v.x; wo[q * 4 + 1] = v.y; wo[q * 4 + 2] = v.z; wo[q * 4 + 3] = v.w;
  }
  float ls = 0.f, lq = 0.f;
  float* mrow = m + (size_t)n * 128;
#pragma unroll
  for (int i = 0; i < 4; ++i) {
    const int l = lg * 4 + i;
    const float* ymr = &yms[(s * 8 + l) * 32];
    float a = 0.f;
#pragma unroll
    for (int q = 0; q < 8; ++q) {
      float4 v = *(const float4*)(ymr + q * 4);
      a = fmaf(v.x, wo[q * 4 + 0], a);
      a = fmaf(v.y, wo[q * 4 + 1], a);
      a = fmaf(v.z, wo[q * 4 + 2], a);
      a = fmaf(v.w, wo[q * 4 + 3], a);
    }
    mrow[l * 16 + e] = a;
    ls += a;
    lq = fmaf(a, a, lq);
  }
#pragma unroll
  for (int off = 32; off > 0; off >>= 1) {
    ls += __shfl_down(ls, off);
    lq += __shfl_down(lq, off);
  }
  const int wid = tid >> 6;
  if ((tid & 63) == 0) { reds[wid * 2] = ls; reds[wid * 2 + 1] = lq; }
  __syncthreads();
  if (tid == 0) {
    float S = reds[0] + reds[2] + reds[4] + reds[6];
    float Q = reds[1] + reds[3] + reds[5] + reds[7];
    int bb = n >> 14;
    int cc = (n >> 7) & 127;
    int gg = cc >> 5;
    atomicAdd(&stats[(bb * 4 + gg) * 2 + 0], S);
    atomicAdd(&stats[(bb * 4 + gg) * 2 + 1], Q);
  }
}

// =====================================================================
// K3: GroupNorm finalize + SiLU + residual, in-place on d_out.
// =====================================================================
__global__ __launch_bounds__(256) void gn_silu_k(
    const float* __restrict__ x,
    const float* __restrict__ gnw, const float* __restrict__ gnb,
    const float* __restrict__ stats, float* __restrict__ out) {
  const int idx0 = (blockIdx.x * 256 + threadIdx.x) * 4;
  const int bb = idx0 >> 21;
  const int cc = (idx0 >> 14) & 127;
  const int gg = cc >> 5;
  const float S = stats[(bb * 4 + gg) * 2 + 0];
  const float Q = stats[(bb * 4 + gg) * 2 + 1];
  const float inv  = 1.0f / 524288.0f;
  const float mu   = S * inv;
  const float var  = fmaf(Q, inv, -mu * mu);
  const float rstd = rsqrtf(var + 1e-5f);
  const float gw  = gnw[cc] * rstd;
  const float gb2 = gnb[cc] - mu * gw;

  float4 mv = *(const float4*)(out + idx0);
  float4 xv = *(const float4*)(x + idx0);
  float mvv[4] = { mv.x, mv.y, mv.z, mv.w };
  float xf[4]  = { xv.x, xv.y, xv.z, xv.w };
  float res[4];
#pragma unroll
  for (int j = 0; j < 4; ++j) {
    float nv = fmaf(mvv[j], gw, gb2);
    float sv = nv * fast_sig(nv);
    res[j] = xf[j] + sv;
  }
  *(float4*)(out + idx0) = make_float4(res[0], res[1], res[2], res[3]);
}

// =====================================================================
extern "C" void kernel_launch(void* const* d_in, const int* in_sizes, int n_in,
                              void* d_out, int out_size, void* d_ws, size_t ws_size,
                              hipStream_t stream) {
  const float* x     = (const float*)d_in[0];
  const float* convw = (const float*)d_in[1];
  const float* convb = (const float*)d_in[2];
  const float* gnw   = (const float*)d_in[3];
  const float* gnb   = (const float*)d_in[4];
  const float* winp  = (const float*)d_in[5];
  const float* c1w   = (const float*)d_in[6];
  const float* c1b   = (const float*)d_in[7];
  const float* xpw   = (const float*)d_in[8];
  const float* dtw   = (const float*)d_in[9];
  const float* dtb   = (const float*)d_in[10];
  const float* alog  = (const float*)d_in[11];
  const float* dvec  = (const float*)d_in[12];
  const float* wout  = (const float*)d_in[13];

  float*  y     = (float*)d_ws;                       // 16 MB
  float*  stats = y + 4194304;                        // 64 B
  // d_out (16 MB) doubles as prep scratch until mamba overwrites it:
  USHORT* xt_g  = (USHORT*)d_out;                     // 8 MB  (x transposed, bf16)
  USHORT* wrep  = (USHORT*)d_out + 4194304;           // 288 KB (weights, bf16)
  float*  m     = (float*)d_out;                      // mamba output, finalized in place

  hipMemsetAsync(stats, 0, 16 * sizeof(float), stream);
  hipLaunchKernelGGL(prep_w_k, dim3(576), dim3(256), 0, stream, convw, wrep);
  hipLaunchKernelGGL(x2t_k, dim3(2048), dim3(256), 0, stream, x, xt_g);
  hipLaunchKernelGGL(conv_mfma_k, dim3(256), dim3(512), 0, stream, xt_g, wrep, convb, y);
  hipLaunchKernelGGL(mamba_k, dim3(4096), dim3(256), 0, stream,
                     y, winp, c1w, c1b, xpw, dtw, dtb, alog, dvec, wout, m, stats);
  hipLaunchKernelGGL(gn_silu_k, dim3(4096), dim3(256), 0, stream,
                     x, gnw, gnb, stats, (float*)d_out);
}